// Round 1
// baseline (439.209 us; speedup 1.0000x reference)
//
#include <hip/hip_runtime.h>
#include <hip/hip_bf16.h>

#define B_  4
#define S_  2048
#define E_  1024
#define H_  16
#define DH_ 64
#define M_  (B_*S_)    // 8192 rows
#define HD_ (H_*DH_)   // 1024

typedef unsigned short u16;
typedef __attribute__((ext_vector_type(8))) __bf16 bf16x8;
typedef __attribute__((ext_vector_type(4))) float  f32x4;

// ---- async global->LDS, 16B per lane (dest must be wave-uniform base + lane*16) ----
__device__ __forceinline__ void g2l16(const void* g, void* l) {
  __builtin_amdgcn_global_load_lds(
      (const __attribute__((address_space(1))) void*)g,
      (__attribute__((address_space(3))) void*)l, 16, 0, 0);
}

// RNE float -> bf16 bits
__device__ __forceinline__ u16 f2bf(float f) {
  union { float f; unsigned u; } v; v.f = f;
  unsigned r = v.u + 0x7FFFu + ((v.u >> 16) & 1u);
  return (u16)(r >> 16);
}

// ---------------- conversion / packing kernels ----------------
__global__ __launch_bounds__(256) void cvt_x_kernel(const float* __restrict__ x,
                                                    u16* __restrict__ xb) {
  int i = blockIdx.x * 256 + threadIdx.x;          // exactly M_*E_/4 threads
  float4 v = ((const float4*)x)[i];
  ushort4 o;
  o.x = f2bf(v.x); o.y = f2bf(v.y); o.z = f2bf(v.z); o.w = f2bf(v.w);
  ((ushort4*)xb)[i] = o;
}

// wqkvT[c][e], c = p*1024 + h*64 + d  (B^T layout for the GEMM)
__global__ __launch_bounds__(256) void pack_wqkv_kernel(
    const float* __restrict__ Wq, const float* __restrict__ Wk,
    const float* __restrict__ Wv, u16* __restrict__ wt) {
  __shared__ u16 tile[64][66];
  int p = blockIdx.z, h = blockIdx.y, e0 = blockIdx.x * 64;
  const float* src = (p == 0 ? Wq : (p == 1 ? Wk : Wv)) + h * (E_ * DH_);
  int tid = threadIdx.x;
#pragma unroll
  for (int r = 0; r < 16; ++r) {
    int idx = r * 256 + tid;
    int el = idx >> 6, d = idx & 63;
    tile[el][d] = f2bf(src[(e0 + el) * DH_ + d]);
  }
  __syncthreads();
  u16* dst = wt + (p * HD_ + h * DH_) * E_;
#pragma unroll
  for (int r = 0; r < 16; ++r) {
    int idx = r * 256 + tid;
    int d = idx >> 6, el = idx & 63;
    dst[d * E_ + e0 + el] = tile[el][d];
  }
}

// woT[e][c] = Wo[c][e]
__global__ __launch_bounds__(256) void pack_wo_kernel(const float* __restrict__ Wo,
                                                      u16* __restrict__ wt) {
  __shared__ u16 tile[64][66];
  int c0 = blockIdx.y * 64, e0 = blockIdx.x * 64;
  int tid = threadIdx.x;
#pragma unroll
  for (int r = 0; r < 16; ++r) {
    int idx = r * 256 + tid;
    int cl = idx >> 6, el = idx & 63;
    tile[cl][el] = f2bf(Wo[(c0 + cl) * E_ + e0 + el]);
  }
  __syncthreads();
#pragma unroll
  for (int r = 0; r < 16; ++r) {
    int idx = r * 256 + tid;
    int er = idx >> 6, cl = idx & 63;
    wt[(e0 + er) * HD_ + c0 + cl] = tile[cl][er];
  }
}

__global__ __launch_bounds__(256) void pack_bias_kernel(
    const float* __restrict__ bq, const float* __restrict__ bk,
    const float* __restrict__ bv, float* __restrict__ bb) {
  int i = blockIdx.x * 256 + threadIdx.x;          // 3072 threads
  const float* s = (i < 1024 ? bq : (i < 2048 ? bk : bv));
  bb[i] = s[i & 1023];
}

// ---------------- GEMM: C[M][N] = A[M][K] * Bt[N][K]^T, K = 1024 ----------------
// 128x128 tile, BK=32, 4 waves (2x2), 16 MFMA 16x16x32 per wave per K-step.
// XOR-swizzled LDS (chunk col ^ (row&3)) keeps global_load_lds contiguous while
// reducing ds_read_b128 conflicts.
// MODE 0: QKV epilogue (bias + scatter to Q[b,s,h,d], K[b,s,h,d], V^T[b,h,d,s], bf16)
// MODE 1: out-proj epilogue (bias + fp32 store)
template <int MODE>
__global__ __launch_bounds__(256) void gemm_bt_kernel(
    const u16* __restrict__ A, const u16* __restrict__ Bt,
    const float* __restrict__ bias,
    u16* __restrict__ oQ, u16* __restrict__ oK, u16* __restrict__ oV,
    float* __restrict__ oF) {
  constexpr int K = 1024;
  __shared__ __align__(16) u16 As[128 * 32];
  __shared__ __align__(16) u16 Bs[128 * 32];
  const int tid = threadIdx.x;
  const int lane = tid & 63, wv = tid >> 6;
  const int wm = (wv >> 1) * 64, wn = (wv & 1) * 64;
  const int q4 = lane >> 4, lm = lane & 15;
  const int tileM = blockIdx.y * 128, tileN = blockIdx.x * 128;

  const int c0 = tid, c1 = tid + 256;
  const u16* gA0 = A + (tileM + (c0 >> 2)) * K + (((c0 & 3) ^ ((c0 >> 2) & 3)) * 8);
  const u16* gA1 = A + (tileM + (c1 >> 2)) * K + (((c1 & 3) ^ ((c1 >> 2) & 3)) * 8);
  const u16* gB0 = Bt + (tileN + (c0 >> 2)) * K + (((c0 & 3) ^ ((c0 >> 2) & 3)) * 8);
  const u16* gB1 = Bt + (tileN + (c1 >> 2)) * K + (((c1 & 3) ^ ((c1 >> 2) & 3)) * 8);
  u16* lA0 = As + c0 * 8; u16* lA1 = As + c1 * 8;
  u16* lB0 = Bs + c0 * 8; u16* lB1 = Bs + c1 * 8;

  f32x4 acc[4][4] = {};

  int aoff[4], boff[4];
#pragma unroll
  for (int i = 0; i < 4; ++i) {
    int ra = wm + i * 16 + lm;
    aoff[i] = ra * 32 + ((q4 ^ (ra & 3)) * 8);
    int rb = wn + i * 16 + lm;
    boff[i] = rb * 32 + ((q4 ^ (rb & 3)) * 8);
  }

  for (int k0 = 0; k0 < K; k0 += 32) {
    g2l16(gA0 + k0, lA0);
    g2l16(gA1 + k0, lA1);
    g2l16(gB0 + k0, lB0);
    g2l16(gB1 + k0, lB1);
    __syncthreads();
    bf16x8 af[4], bf[4];
#pragma unroll
    for (int i = 0; i < 4; ++i) af[i] = *(const bf16x8*)(As + aoff[i]);
#pragma unroll
    for (int j = 0; j < 4; ++j) bf[j] = *(const bf16x8*)(Bs + boff[j]);
#pragma unroll
    for (int i = 0; i < 4; ++i)
#pragma unroll
      for (int j = 0; j < 4; ++j)
        acc[i][j] = __builtin_amdgcn_mfma_f32_16x16x32_bf16(af[i], bf[j], acc[i][j], 0, 0, 0);
    __syncthreads();
  }

  // epilogue; C/D layout: col = lane&15, row = q4*4 + r  [m89/m91]
#pragma unroll
  for (int j = 0; j < 4; ++j) {
    int n = tileN + wn + j * 16 + lm;
    float bs = bias[n];
#pragma unroll
    for (int i = 0; i < 4; ++i) {
#pragma unroll
      for (int r = 0; r < 4; ++r) {
        int m = tileM + wm + i * 16 + q4 * 4 + r;
        float val = acc[i][j][r] + bs;
        if (MODE == 1) {
          oF[m * HD_ + n] = val;
        } else {
          int proj = n >> 10, cc = n & 1023;   // proj uniform per block (tileN 128-aligned)
          u16 hv = f2bf(val);
          if (proj == 0)      oQ[m * 1024 + cc] = hv;
          else if (proj == 1) oK[m * 1024 + cc] = hv;
          else {
            int bb = m >> 11, ss = m & 2047, hh = cc >> 6, dd = cc & 63;
            oV[((bb * H_ + hh) * DH_ + dd) * S_ + ss] = hv;   // V transposed [b,h,d,s]
          }
        }
      }
    }
  }
}

// ---------------- flash attention ----------------
// Block: 64 Q-rows for one (b,h); 4 waves x 16 rows. K/V tiles of 64 keys, 32 iters.
// V is pre-transposed [b,h,d,s] so its B-operand frags are contiguous in LDS.
__global__ __launch_bounds__(256) void flash_kernel(
    const u16* __restrict__ Q, const u16* __restrict__ Kb,
    const u16* __restrict__ Vt, u16* __restrict__ Z) {
  __shared__ __align__(16) u16 Qs[64 * 64];
  __shared__ __align__(16) u16 Ks[64 * 64];
  __shared__ __align__(16) u16 Vs[64 * 64];   // [d][key]
  __shared__ __align__(16) u16 Ps[4 * 16 * 64];  // per-wave P buffers
  const int tid = threadIdx.x, lane = tid & 63, wv = tid >> 6;
  const int q4 = lane >> 4, lm = lane & 15;
  const int b = blockIdx.z, h = blockIdx.y, qt = blockIdx.x;
  const u16* qbase = Q + (b * S_ + qt * 64) * HD_ + h * DH_;
  const u16* kbase = Kb + b * S_ * HD_ + h * DH_;
  const u16* vbase = Vt + (b * H_ + h) * DH_ * S_;
  u16* zbase = Z + (b * S_ + qt * 64) * HD_ + h * DH_;

  {
    int c = tid;
    g2l16(qbase + (c >> 3) * HD_ + (((c & 7) ^ ((c >> 3) & 7)) * 8), Qs + c * 8);
    c = tid + 256;
    g2l16(qbase + (c >> 3) * HD_ + (((c & 7) ^ ((c >> 3) & 7)) * 8), Qs + c * 8);
  }
  __syncthreads();

  bf16x8 aq[2];
  {
    int r = wv * 16 + lm;
    aq[0] = *(const bf16x8*)(Qs + r * 64 + ((q4 ^ (r & 7)) * 8));
    aq[1] = *(const bf16x8*)(Qs + r * 64 + (((4 + q4) ^ (r & 7)) * 8));
  }

  float mi[4] = {-1e30f, -1e30f, -1e30f, -1e30f};
  float li[4] = {0.f, 0.f, 0.f, 0.f};
  f32x4 oacc[4] = {};
  u16* Pw = Ps + wv * (16 * 64);

  for (int t = 0; t < 32; ++t) {
    {
      int c = tid;
      g2l16(kbase + (t * 64 + (c >> 3)) * HD_ + (((c & 7) ^ ((c >> 3) & 7)) * 8), Ks + c * 8);
      g2l16(vbase + (c >> 3) * S_ + t * 64 + (((c & 7) ^ ((c >> 3) & 7)) * 8), Vs + c * 8);
      c = tid + 256;
      g2l16(kbase + (t * 64 + (c >> 3)) * HD_ + (((c & 7) ^ ((c >> 3) & 7)) * 8), Ks + c * 8);
      g2l16(vbase + (c >> 3) * S_ + t * 64 + (((c & 7) ^ ((c >> 3) & 7)) * 8), Vs + c * 8);
    }
    __syncthreads();

    // S = Q*K^T
    f32x4 sacc[4] = {};
#pragma unroll
    for (int j = 0; j < 4; ++j) {
      int r = j * 16 + lm;
      bf16x8 k0 = *(const bf16x8*)(Ks + r * 64 + ((q4 ^ (r & 7)) * 8));
      bf16x8 k1 = *(const bf16x8*)(Ks + r * 64 + (((4 + q4) ^ (r & 7)) * 8));
      sacc[j] = __builtin_amdgcn_mfma_f32_16x16x32_bf16(aq[0], k0, sacc[j], 0, 0, 0);
      sacc[j] = __builtin_amdgcn_mfma_f32_16x16x32_bf16(aq[1], k1, sacc[j], 0, 0, 0);
    }
#pragma unroll
    for (int j = 0; j < 4; ++j)
#pragma unroll
      for (int r = 0; r < 4; ++r) sacc[j][r] *= 0.125f;   // 1/sqrt(64)

    // online softmax; row r lives in the 16 lanes of this quad-group
    float alpha[4], p[4][4];
#pragma unroll
    for (int r = 0; r < 4; ++r) {
      float v = fmaxf(fmaxf(sacc[0][r], sacc[1][r]), fmaxf(sacc[2][r], sacc[3][r]));
      v = fmaxf(v, __shfl_xor(v, 1));
      v = fmaxf(v, __shfl_xor(v, 2));
      v = fmaxf(v, __shfl_xor(v, 4));
      v = fmaxf(v, __shfl_xor(v, 8));
      float mnew = fmaxf(mi[r], v);
      alpha[r] = __expf(mi[r] - mnew);
      mi[r] = mnew;
    }
#pragma unroll
    for (int j = 0; j < 4; ++j)
#pragma unroll
      for (int r = 0; r < 4; ++r) p[j][r] = __expf(sacc[j][r] - mi[r]);
#pragma unroll
    for (int r = 0; r < 4; ++r) {
      float s = p[0][r] + p[1][r] + p[2][r] + p[3][r];
      s += __shfl_xor(s, 1);
      s += __shfl_xor(s, 2);
      s += __shfl_xor(s, 4);
      s += __shfl_xor(s, 8);
      li[r] = li[r] * alpha[r] + s;
    }
#pragma unroll
    for (int jd = 0; jd < 4; ++jd)
#pragma unroll
      for (int r = 0; r < 4; ++r) oacc[jd][r] *= alpha[r];

    // P: C-layout -> LDS (swizzled) -> A-layout frags (wave-private buffer)
#pragma unroll
    for (int j = 0; j < 4; ++j) {
#pragma unroll
      for (int r = 0; r < 4; ++r) {
        int row = q4 * 4 + r;
        int col = j * 16 + lm;
        int ch = col >> 3, we = col & 7;
        Pw[row * 64 + ((ch ^ (row & 7)) * 8 + we)] = f2bf(p[j][r]);
      }
    }
    asm volatile("s_waitcnt lgkmcnt(0)" ::: "memory");  // wave-private: no barrier needed
    bf16x8 pa0, pa1;
    {
      int r = lm;
      pa0 = *(const bf16x8*)(Pw + r * 64 + ((q4 ^ (r & 7)) * 8));
      pa1 = *(const bf16x8*)(Pw + r * 64 + (((4 + q4) ^ (r & 7)) * 8));
    }
#pragma unroll
    for (int jd = 0; jd < 4; ++jd) {
      int rv = jd * 16 + lm;
      bf16x8 v0 = *(const bf16x8*)(Vs + rv * 64 + ((q4 ^ (rv & 7)) * 8));
      bf16x8 v1 = *(const bf16x8*)(Vs + rv * 64 + (((4 + q4) ^ (rv & 7)) * 8));
      oacc[jd] = __builtin_amdgcn_mfma_f32_16x16x32_bf16(pa0, v0, oacc[jd], 0, 0, 0);
      oacc[jd] = __builtin_amdgcn_mfma_f32_16x16x32_bf16(pa1, v1, oacc[jd], 0, 0, 0);
    }
    __syncthreads();
  }

#pragma unroll
  for (int jd = 0; jd < 4; ++jd) {
#pragma unroll
    for (int r = 0; r < 4; ++r) {
      int row = wv * 16 + q4 * 4 + r;
      zbase[row * HD_ + jd * 16 + lm] = f2bf(oacc[jd][r] / li[r]);
    }
  }
}

// ---------------- host ----------------
extern "C" void kernel_launch(void* const* d_in, const int* in_sizes, int n_in,
                              void* d_out, int out_size, void* d_ws, size_t ws_size,
                              hipStream_t stream) {
  const float* x  = (const float*)d_in[0];
  const float* Wq = (const float*)d_in[1];
  const float* bq = (const float*)d_in[2];
  const float* Wk = (const float*)d_in[3];
  const float* bk = (const float*)d_in[4];
  const float* Wv = (const float*)d_in[5];
  const float* bv = (const float*)d_in[6];
  const float* Wo = (const float*)d_in[7];
  const float* bo = (const float*)d_in[8];
  float* out = (float*)d_out;

  char* w = (char*)d_ws;   // total ~88.5 MB
  u16*   xb    = (u16*)w;   w += (size_t)M_ * E_ * 2;
  u16*   wqkvT = (u16*)w;   w += (size_t)3 * HD_ * E_ * 2;
  u16*   woT   = (u16*)w;   w += (size_t)E_ * HD_ * 2;
  float* bqkv  = (float*)w; w += (size_t)3 * HD_ * 4;
  u16*   qB    = (u16*)w;   w += (size_t)M_ * HD_ * 2;
  u16*   kB    = (u16*)w;   w += (size_t)M_ * HD_ * 2;
  u16*   vT    = (u16*)w;   w += (size_t)M_ * HD_ * 2;
  u16*   zB    = (u16*)w;   w += (size_t)M_ * HD_ * 2;

  cvt_x_kernel<<<dim3(M_ * E_ / 4 / 256), 256, 0, stream>>>(x, xb);
  pack_wqkv_kernel<<<dim3(16, 16, 3), 256, 0, stream>>>(Wq, Wk, Wv, wqkvT);
  pack_wo_kernel<<<dim3(16, 16), 256, 0, stream>>>(Wo, woT);
  pack_bias_kernel<<<dim3(12), 256, 0, stream>>>(bq, bk, bv, bqkv);
  gemm_bt_kernel<0><<<dim3(24, 64), 256, 0, stream>>>(xb, wqkvT, bqkv, qB, kB, vT, nullptr);
  flash_kernel<<<dim3(32, 16, 4), 256, 0, stream>>>(qB, kB, vT, zB);
  gemm_bt_kernel<1><<<dim3(8, 64), 256, 0, stream>>>(zB, woT, bo, nullptr, nullptr, nullptr, out);
}